// Round 2
// baseline (142.388 us; speedup 1.0000x reference)
//
#include <hip/hip_runtime.h>

#define FDIM 256
#define H1D  256
#define H2D  128
#define BATCH 4096
#define BM   64
#define FPB  8
#define NBT  (BATCH / BM)   // 64 batch tiles
#define NFG  (FDIM / FPB)   // 32 feature groups

typedef _Float16 half8 __attribute__((ext_vector_type(8)));
typedef float    f32x4 __attribute__((ext_vector_type(4)));

// ---------------------------------------------------------------------------
// Prep: W2 (F,H1,H2) fp32 -> f16 MFMA B-fragment-linear layout in ws.
// Fragment (f, s, t): k = 32s + kpat(g,j), n = 16t + (lane&15),
// kpat(g,j) = 4g + j (j<4) | 16 + 4g + (j-4) (j>=4), g = lane>>4.
// Stored as 64 lanes x 8 halves contiguous (16B/lane) -> coalesced b128 loads.
// ---------------------------------------------------------------------------
__global__ __launch_bounds__(512) void prep_w2(const float* __restrict__ W2,
                                               _Float16* __restrict__ w2f) {
    const int f    = blockIdx.x >> 3;
    const int s    = blockIdx.x & 7;
    const int t    = threadIdx.x >> 6;
    const int lane = threadIdx.x & 63;
    const int g    = lane >> 4;
    const int ln   = lane & 15;
    const int n    = t * 16 + ln;
    half8 v;
#pragma unroll
    for (int j = 0; j < 8; ++j) {
        const int k = s * 32 + 4 * g + (j < 4 ? j : 12 + j);
        v[j] = (_Float16)W2[(f * H1D + k) * H2D + n];
    }
    *(half8*)(w2f + (size_t)(((f * 8 + s) * 8 + t) * 64 + lane) * 8) = v;
}

// ---------------------------------------------------------------------------
// Main fused kernel: per block = (feature group fg, batch tile bt).
// For each of FPB features: layer1 -> LDS (f16, K-permuted + XOR-swizzled),
// layer2 via mfma_f32_16x16x32_f16, layer3 epilogue accumulated in registers.
// Deterministic: partials written to ws, reduced by reduce_out.
// ---------------------------------------------------------------------------
__global__ __launch_bounds__(256) void coxnam_main(
    const float* __restrict__ x,  const float* __restrict__ W1,
    const float* __restrict__ b1, const float* __restrict__ b2,
    const float* __restrict__ W3, const _Float16* __restrict__ w2f,
    float* __restrict__ partial) {
    __shared__ _Float16 h1[BM * H1D];   // 32 KB
    __shared__ float red[4][BM];        // 1 KB

    const int tid  = threadIdx.x;
    const int wave = tid >> 6;
    const int lane = tid & 63;
    const int g    = lane >> 4;
    const int ln   = lane & 15;
    const int fg   = blockIdx.x / NBT;
    const int bt   = blockIdx.x % NBT;
    const int b0   = bt * BM;
    const int brow = tid & 63;          // row this thread fills in layer-1

    float sacc[4][4];
#pragma unroll
    for (int mi = 0; mi < 4; ++mi)
#pragma unroll
        for (int r = 0; r < 4; ++r) sacc[mi][r] = 0.f;

    for (int fi = 0; fi < FPB; ++fi) {
        const int f = fg * FPB + fi;
        const float xv = x[(size_t)(b0 + brow) * FDIM + f];
        __syncthreads();  // previous feature's GEMM done reading h1

        // ---- layer 1: h1[b][k] = relu(x[b]*W1[f][k] + b1[f][k]) ----
        // Written in K-permuted order so each 16B slot holds kpat(g,0..7),
        // XOR-swizzled by row so fragment ds_read_b128 is bank-uniform.
#pragma unroll
        for (int it = 0; it < 8; ++it) {
            const int cg = it * 4 + wave;        // 0..31  (c = k-chunk, gg = group)
            const int c  = cg >> 2, gg = cg & 3;
            const float4 wlo = *(const float4*)(W1 + f * H1D + c * 32 + gg * 4);
            const float4 whi = *(const float4*)(W1 + f * H1D + c * 32 + 16 + gg * 4);
            const float4 blo = *(const float4*)(b1 + f * H1D + c * 32 + gg * 4);
            const float4 bhi = *(const float4*)(b1 + f * H1D + c * 32 + 16 + gg * 4);
            half8 hv;
            hv[0] = (_Float16)fmaxf(fmaf(xv, wlo.x, blo.x), 0.f);
            hv[1] = (_Float16)fmaxf(fmaf(xv, wlo.y, blo.y), 0.f);
            hv[2] = (_Float16)fmaxf(fmaf(xv, wlo.z, blo.z), 0.f);
            hv[3] = (_Float16)fmaxf(fmaf(xv, wlo.w, blo.w), 0.f);
            hv[4] = (_Float16)fmaxf(fmaf(xv, whi.x, bhi.x), 0.f);
            hv[5] = (_Float16)fmaxf(fmaf(xv, whi.y, bhi.y), 0.f);
            hv[6] = (_Float16)fmaxf(fmaf(xv, whi.z, bhi.z), 0.f);
            hv[7] = (_Float16)fmaxf(fmaf(xv, whi.w, bhi.w), 0.f);
            int byte = brow * 512 + c * 64 + gg * 16;
            byte ^= (brow & 7) << 4;
            *(half8*)((char*)h1 + byte) = hv;
        }
        __syncthreads();

        // ---- layer 2: (64x256) @ (256x128), wave w owns n-cols [32w,32w+32) ----
        f32x4 acc[4][2];
#pragma unroll
        for (int mi = 0; mi < 4; ++mi)
#pragma unroll
            for (int q = 0; q < 2; ++q) acc[mi][q] = (f32x4){0.f, 0.f, 0.f, 0.f};

        const _Float16* w2base = w2f + (size_t)(f * 64 + 2 * wave) * 512 + lane * 8;
#pragma unroll
        for (int s = 0; s < 8; ++s) {
            half8 bf[2];
#pragma unroll
            for (int q = 0; q < 2; ++q)
                bf[q] = *(const half8*)(w2base + (size_t)(s * 8 + q) * 512);
#pragma unroll
            for (int mi = 0; mi < 4; ++mi) {
                const int row = mi * 16 + ln;
                int byte = row * 512 + s * 64 + g * 16;
                byte ^= (row & 7) << 4;
                const half8 af = *(const half8*)((const char*)h1 + byte);
#pragma unroll
                for (int q = 0; q < 2; ++q)
                    acc[mi][q] = __builtin_amdgcn_mfma_f32_16x16x32_f16(
                        af, bf[q], acc[mi][q], 0, 0, 0);
            }
        }

        // ---- layer 3 epilogue: relu(acc + b2) . W3, accumulate over features ----
        const int n0 = wave * 32 + ln;
        const float b2a = b2[f * H2D + n0], b2b = b2[f * H2D + n0 + 16];
        const float w3a = W3[f * H2D + n0], w3b = W3[f * H2D + n0 + 16];
#pragma unroll
        for (int mi = 0; mi < 4; ++mi)
#pragma unroll
            for (int r = 0; r < 4; ++r) {
                const float va = fmaxf(acc[mi][0][r] + b2a, 0.f);
                const float vb = fmaxf(acc[mi][1][r] + b2b, 0.f);
                sacc[mi][r] = fmaf(va, w3a, fmaf(vb, w3b, sacc[mi][r]));
            }
    }

    // ---- reduce over the 16 n-lanes of each group ----
#pragma unroll
    for (int mi = 0; mi < 4; ++mi)
#pragma unroll
        for (int r = 0; r < 4; ++r) {
            float v = sacc[mi][r];
            v += __shfl_xor(v, 1, 16);
            v += __shfl_xor(v, 2, 16);
            v += __shfl_xor(v, 4, 16);
            v += __shfl_xor(v, 8, 16);
            sacc[mi][r] = v;
        }
    __syncthreads();
    if (ln == 0) {
#pragma unroll
        for (int mi = 0; mi < 4; ++mi)
#pragma unroll
            for (int r = 0; r < 4; ++r)
                red[wave][mi * 16 + g * 4 + r] = sacc[mi][r];
    }
    __syncthreads();
    if (tid < BM) {
        const float v = red[0][tid] + red[1][tid] + red[2][tid] + red[3][tid];
        partial[fg * BATCH + b0 + tid] = v;
    }
}

// ---------------------------------------------------------------------------
// Final reduction over feature groups + sum of b3.
// ---------------------------------------------------------------------------
__global__ __launch_bounds__(256) void reduce_out(const float* __restrict__ partial,
                                                  const float* __restrict__ b3,
                                                  float* __restrict__ out) {
    const int b = blockIdx.x * 256 + threadIdx.x;
    float v = 0.f;
#pragma unroll
    for (int fgi = 0; fgi < NFG; ++fgi) v += partial[fgi * BATCH + b];
    float sb3 = 0.f;
#pragma unroll 4
    for (int f4 = 0; f4 < FDIM; f4 += 4) {
        const float4 t = *(const float4*)(b3 + f4);
        sb3 += t.x + t.y + t.z + t.w;
    }
    out[b] = v + sb3;
}

extern "C" void kernel_launch(void* const* d_in, const int* in_sizes, int n_in,
                              void* d_out, int out_size, void* d_ws, size_t ws_size,
                              hipStream_t stream) {
    const float* x  = (const float*)d_in[0];
    const float* W1 = (const float*)d_in[1];
    const float* b1 = (const float*)d_in[2];
    const float* W2 = (const float*)d_in[3];
    const float* b2 = (const float*)d_in[4];
    const float* W3 = (const float*)d_in[5];
    const float* b3 = (const float*)d_in[6];

    const size_t w2f_elems = (size_t)FDIM * H1D * H2D;          // 8.4M f16 = 16 MB
    _Float16* w2f   = (_Float16*)d_ws;
    float* partial  = (float*)((char*)d_ws + w2f_elems * sizeof(_Float16));
    if (ws_size < w2f_elems * sizeof(_Float16) + (size_t)NFG * BATCH * sizeof(float))
        return;  // insufficient scratch; fail visibly

    prep_w2<<<FDIM * 8, 512, 0, stream>>>(W2, w2f);
    coxnam_main<<<NFG * NBT, 256, 0, stream>>>(x, W1, b1, b2, W3, w2f, partial);
    reduce_out<<<BATCH / 256, 256, 0, stream>>>(partial, b3, (float*)d_out);
}

// Round 3
// 122.700 us; speedup vs baseline: 1.1605x; 1.1605x over previous
//
#include <hip/hip_runtime.h>

#define FDIM 256
#define H1D  256
#define H2D  128
#define BATCH 4096
#define BM   128
#define FPB  8
#define NBT  (BATCH / BM)   // 32 batch tiles
#define NFG  (FDIM / FPB)   // 32 feature groups

typedef _Float16 half8 __attribute__((ext_vector_type(8)));
typedef float    f32x4 __attribute__((ext_vector_type(4)));

// ---------------------------------------------------------------------------
// Prep: W2 (F,H1,H2) fp32 -> f16 MFMA B-fragment-linear layout in ws.
// Fragment (f, s, t): k = 32s + kpat(g,j), n = 16t + (lane&15),
// kpat(g,j) = 4g + j (j<4) | 16 + 4g + (j-4) (j>=4), g = lane>>4.
// ---------------------------------------------------------------------------
__global__ __launch_bounds__(512) void prep_w2(const float* __restrict__ W2,
                                               _Float16* __restrict__ w2f) {
    const int f    = blockIdx.x >> 3;
    const int s    = blockIdx.x & 7;
    const int t    = threadIdx.x >> 6;
    const int lane = threadIdx.x & 63;
    const int g    = lane >> 4;
    const int ln   = lane & 15;
    const int n    = t * 16 + ln;
    half8 v;
#pragma unroll
    for (int j = 0; j < 8; ++j) {
        const int k = s * 32 + 4 * g + (j < 4 ? j : 12 + j);
        v[j] = (_Float16)W2[(f * H1D + k) * H2D + n];
    }
    *(half8*)(w2f + (size_t)(((f * 8 + s) * 8 + t) * 64 + lane) * 8) = v;
}

// ---------------------------------------------------------------------------
// Main: 2-wave blocks, BM=128 batch rows, wave w owns n-cols [64w, 64w+64).
// k-chunk (32-wide) double-buffered h1 in LDS; per chunk: load B frags
// (global, L2), stage next chunk (scalar W1/b1 loads + VALU -> ds_write),
// 8x4 MFMA on current chunk, one barrier. Epilogue folds relu(.)+dot(W3)
// into sacc per feature. Deterministic partials -> reduce_out.
// ---------------------------------------------------------------------------
__global__ __launch_bounds__(128, 2) void coxnam_main(
    const float* __restrict__ x,  const float* __restrict__ W1,
    const float* __restrict__ b1, const float* __restrict__ b2,
    const float* __restrict__ W3, const _Float16* __restrict__ w2f,
    float* __restrict__ partial) {
    __shared__ _Float16 h1[2][BM * 32];   // 2 x 8 KB
    __shared__ float red[2][BM];

    const int t    = threadIdx.x;
    const int w    = t >> 6;
    const int lane = t & 63;
    const int g    = lane >> 4;
    const int ln   = lane & 15;
    // XCD-aware bijective swizzle (grid 1024 = 8*128): fg-contiguous per XCD
    const int wg = (blockIdx.x & 7) * 128 + (blockIdx.x >> 3);
    const int fg = wg >> 5, bt = wg & 31, b0 = bt * BM;

    f32x4 acc[8][4];
    float sacc[8][4];
#pragma unroll
    for (int mi = 0; mi < 8; ++mi)
#pragma unroll
        for (int qt = 0; qt < 4; ++qt) {
            acc[mi][qt] = (f32x4){0.f, 0.f, 0.f, 0.f};
            sacc[mi][qt] = 0.f;
        }

    // stage one 32-k chunk of layer 1 into h1[buf]; thread t owns row t.
    // slot swizzle g^((t>>1)&3): conflict-free b128 writes AND reads.
    auto stage = [&](int f, int s, int buf, float xv) {
        const float* w1p = W1 + f * H1D + s * 32;
        const float* b1p = b1 + f * H1D + s * 32;
        char* base = (char*)&h1[buf][0] + t * 64;
#pragma unroll
        for (int gq = 0; gq < 4; ++gq) {
            const float4 wlo = *(const float4*)(w1p + 4 * gq);
            const float4 whi = *(const float4*)(w1p + 16 + 4 * gq);
            const float4 blo = *(const float4*)(b1p + 4 * gq);
            const float4 bhi = *(const float4*)(b1p + 16 + 4 * gq);
            half8 hv;
            hv[0] = (_Float16)fmaxf(fmaf(xv, wlo.x, blo.x), 0.f);
            hv[1] = (_Float16)fmaxf(fmaf(xv, wlo.y, blo.y), 0.f);
            hv[2] = (_Float16)fmaxf(fmaf(xv, wlo.z, blo.z), 0.f);
            hv[3] = (_Float16)fmaxf(fmaf(xv, wlo.w, blo.w), 0.f);
            hv[4] = (_Float16)fmaxf(fmaf(xv, whi.x, bhi.x), 0.f);
            hv[5] = (_Float16)fmaxf(fmaf(xv, whi.y, bhi.y), 0.f);
            hv[6] = (_Float16)fmaxf(fmaf(xv, whi.z, bhi.z), 0.f);
            hv[7] = (_Float16)fmaxf(fmaf(xv, whi.w, bhi.w), 0.f);
            const int slot = gq ^ ((t >> 1) & 3);
            *(half8*)(base + slot * 16) = hv;
        }
    };

    float xcur = x[(size_t)(b0 + t) * FDIM + fg * FPB];
    stage(fg * FPB, 0, 0, xcur);
    __syncthreads();

    for (int fi = 0; fi < FPB; ++fi) {
        const int f = fg * FPB + fi;
        const float xnext =
            (fi + 1 < FPB) ? x[(size_t)(b0 + t) * FDIM + f + 1] : 0.f;
#pragma unroll
        for (int s = 0; s < 8; ++s) {
            const int buf = s & 1;
            // B fragments for this chunk (global, L2-resident w2f)
            half8 bf[4];
            const _Float16* bp =
                w2f + ((size_t)(f * 8 + s) * 8 + w * 4) * 512 + lane * 8;
#pragma unroll
            for (int qt = 0; qt < 4; ++qt)
                bf[qt] = *(const half8*)(bp + (size_t)qt * 512);
            // stage next chunk into the other buffer (overlaps B latency)
            if (s < 7)
                stage(f, s + 1, buf ^ 1, xcur);
            else if (fi + 1 < FPB)
                stage(f + 1, 0, buf ^ 1, xnext);
            // A fragments from LDS + MFMA
            const char* abase = (const char*)&h1[buf][0] + ln * 64 +
                                ((g ^ ((ln >> 1) & 3)) * 16);
#pragma unroll
            for (int mi = 0; mi < 8; ++mi) {
                const half8 af = *(const half8*)(abase + mi * 1024);
#pragma unroll
                for (int qt = 0; qt < 4; ++qt)
                    acc[mi][qt] = __builtin_amdgcn_mfma_f32_16x16x32_f16(
                        af, bf[qt], acc[mi][qt], 0, 0, 0);
            }
            __syncthreads();
        }
        // ---- epilogue: relu(acc + b2) . W3 -> sacc; reset acc ----
        const int nbase = f * H2D + w * 64 + ln;
        float b2v[4], w3v[4];
#pragma unroll
        for (int qt = 0; qt < 4; ++qt) {
            b2v[qt] = b2[nbase + qt * 16];
            w3v[qt] = W3[nbase + qt * 16];
        }
#pragma unroll
        for (int mi = 0; mi < 8; ++mi)
#pragma unroll
            for (int qt = 0; qt < 4; ++qt)
#pragma unroll
                for (int r = 0; r < 4; ++r) {
                    const float v = fmaxf(acc[mi][qt][r] + b2v[qt], 0.f);
                    sacc[mi][r] = fmaf(v, w3v[qt], sacc[mi][r]);
                    acc[mi][qt][r] = 0.f;
                }
        xcur = xnext;
    }

    // ---- reduce over the 16 n-lanes of each group, then across 2 waves ----
#pragma unroll
    for (int mi = 0; mi < 8; ++mi)
#pragma unroll
        for (int r = 0; r < 4; ++r) {
            float v = sacc[mi][r];
            v += __shfl_xor(v, 1, 16);
            v += __shfl_xor(v, 2, 16);
            v += __shfl_xor(v, 4, 16);
            v += __shfl_xor(v, 8, 16);
            if (ln == 0) red[w][mi * 16 + g * 4 + r] = v;
        }
    __syncthreads();
    if (t < BM)
        partial[(size_t)fg * BATCH + b0 + t] = red[0][t] + red[1][t];
}

// ---------------------------------------------------------------------------
// Final reduction over feature groups + sum of b3.
// ---------------------------------------------------------------------------
__global__ __launch_bounds__(256) void reduce_out(const float* __restrict__ partial,
                                                  const float* __restrict__ b3,
                                                  float* __restrict__ out) {
    const int b = blockIdx.x * 256 + threadIdx.x;
    float v = 0.f;
#pragma unroll
    for (int fgi = 0; fgi < NFG; ++fgi) v += partial[fgi * BATCH + b];
    float sb3 = 0.f;
#pragma unroll 4
    for (int f4 = 0; f4 < FDIM; f4 += 4) {
        const float4 t = *(const float4*)(b3 + f4);
        sb3 += t.x + t.y + t.z + t.w;
    }
    out[b] = v + sb3;
}

extern "C" void kernel_launch(void* const* d_in, const int* in_sizes, int n_in,
                              void* d_out, int out_size, void* d_ws, size_t ws_size,
                              hipStream_t stream) {
    const float* x  = (const float*)d_in[0];
    const float* W1 = (const float*)d_in[1];
    const float* b1 = (const float*)d_in[2];
    const float* W2 = (const float*)d_in[3];
    const float* b2 = (const float*)d_in[4];
    const float* W3 = (const float*)d_in[5];
    const float* b3 = (const float*)d_in[6];

    const size_t w2f_elems = (size_t)FDIM * H1D * H2D;   // 16 MB f16
    _Float16* w2f  = (_Float16*)d_ws;
    float* partial = (float*)((char*)d_ws + w2f_elems * sizeof(_Float16));
    if (ws_size < w2f_elems * sizeof(_Float16) + (size_t)NFG * BATCH * sizeof(float))
        return;

    prep_w2<<<FDIM * 8, 512, 0, stream>>>(W2, w2f);
    coxnam_main<<<NFG * NBT, 128, 0, stream>>>(x, W1, b1, b2, W3, w2f, partial);
    reduce_out<<<BATCH / 256, 256, 0, stream>>>(partial, b3, (float*)d_out);
}